// Round 3
// baseline (240.103 us; speedup 1.0000x reference)
//
#include <hip/hip_runtime.h>

#define MARGIN_NEG 0.4f
#define MARGIN_POS 0.01f

// Problem constants: B=64, C=3, H=W=256 -> N = 12,582,912 elems; z: 64 x 16384
#define N_ELEM   12582912
#define BATCH    64
#define DIMZ     16384
#define ROW4     (DIMZ / 4)            // 4096 float4 per z-row

// MSE chunking: each MSE block handles one 16-KB chunk of one (A,B) pair.
// Phase 1: A-chunk -> LDS (async burst). Phase 2: B-chunk -> regs, diff vs LDS.
#define CHUNK_BYTES 16384
#define CHUNK_F4    (CHUNK_BYTES / 16)             // 1024 float4 per chunk
#define CHUNKS_PER_PAIR (N_ELEM * 4 / CHUNK_BYTES) // 3072
#define CB2   1024                                  // contrastive blocks (first)
#define MSEB  (2 * CHUNKS_PER_PAIR)                 // 6144 MSE blocks

// ws layout (floats): [0..4095] = d[m][n] partial sums; [4160] = MSE sq-diff sum
#define WS_MSE_IDX 4160
#define WS_FLOATS  4161

__global__ __launch_bounds__(256) void fused_pass1(
        const float* __restrict__ o1, const float* __restrict__ i1,
        const float* __restrict__ o2, const float* __restrict__ i2,
        const float* __restrict__ z1, const float* __restrict__ z2,
        float* __restrict__ ws) {
    __shared__ __align__(16) float4 smem[CHUNK_F4];   // 16 KB
    const int b = blockIdx.x;
    const int t = threadIdx.x;
    const int lane = t & 63, wid = t >> 6;

    if (b >= CB2) {
        // ---------------- MSE: staged single-stream bursts ----------------
        const int mb   = b - CB2;
        const int pair = mb & 1;
        const int chunk = mb >> 1;                    // 0..3071
        const float4* A  = pair ? (const float4*)o2 : (const float4*)o1;
        const float4* Bv = pair ? (const float4*)i2 : (const float4*)i1;
        const int base = chunk * CHUNK_F4;            // float4 index of chunk start

        // Phase 1: burst A-chunk (16 KB, contiguous, single buffer) -> LDS.
        // LDS dest per instr is wave-uniform base + lane*16 (HW rule), so
        // lds offset = i*4096 + wid*1024 gives an identity A->LDS mapping.
        #pragma unroll
        for (int i = 0; i < 4; i++) {
            const float4* g = A + (base + i * 256 + t);
            char* l = (char*)smem + i * 4096 + wid * 1024;
            __builtin_amdgcn_global_load_lds(
                (const __attribute__((address_space(1))) void*)g,
                (__attribute__((address_space(3))) void*)l, 16, 0, 0);
        }
        // Hard temporal separation: A-burst fully lands before B-burst issues.
        __builtin_amdgcn_sched_barrier(0);
        asm volatile("s_waitcnt vmcnt(0)" ::: "memory");
        __builtin_amdgcn_sched_barrier(0);

        // Phase 2: burst B-chunk (16 KB, contiguous, single buffer) -> regs.
        float4 bb[4];
        #pragma unroll
        for (int i = 0; i < 4; i++) bb[i] = Bv[base + i * 256 + t];

        float acc = 0.f;
        #pragma unroll
        for (int i = 0; i < 4; i++) {
            float4 a = smem[i * 256 + t];
            float dx = a.x - bb[i].x, dy = a.y - bb[i].y;
            float dz = a.z - bb[i].z, dw = a.w - bb[i].w;
            acc += dx * dx + dy * dy + dz * dz + dw * dw;
        }

        #pragma unroll
        for (int off = 32; off > 0; off >>= 1) acc += __shfl_down(acc, off, 64);
        __shared__ float ws4[4];
        if (lane == 0) ws4[wid] = acc;
        __syncthreads();
        if (t == 0) atomicAdd(&ws[WS_MSE_IDX], ws4[0] + ws4[1] + ws4[2] + ws4[3]);
    } else {
        // ---- contrastive pass 1: partial sums of sum_k (z1[m,k]-z2[n,k])^2 ----
        const int kc   = b & 3;            // k-chunk: 1024 float4 = 4096 floats
        const int tile = b >> 2;           // 0..255
        const int m0 = (tile >> 4) * 4;
        const int n0 = (tile & 15) * 4;
        const float4* z1v = (const float4*)z1;
        const float4* z2v = (const float4*)z2;

        float acc[16];
        #pragma unroll
        for (int p = 0; p < 16; p++) acc[p] = 0.f;

        const int cbase = kc * 1024 + t;
        #pragma unroll
        for (int it = 0; it < 4; it++) {
            const int c = cbase + it * 256;
            float4 a[4], bz[4];
            #pragma unroll
            for (int i = 0; i < 4; i++) a[i] = z1v[(m0 + i) * ROW4 + c];
            #pragma unroll
            for (int j = 0; j < 4; j++) bz[j] = z2v[(n0 + j) * ROW4 + c];
            #pragma unroll
            for (int i = 0; i < 4; i++) {
                #pragma unroll
                for (int j = 0; j < 4; j++) {
                    float dx = a[i].x - bz[j].x, dy = a[i].y - bz[j].y;
                    float dz = a[i].z - bz[j].z, dw = a[i].w - bz[j].w;
                    acc[i * 4 + j] += dx * dx + dy * dy + dz * dz + dw * dw;
                }
            }
        }

        __shared__ float wsum[4][16];
        #pragma unroll
        for (int p = 0; p < 16; p++) {
            float v = acc[p];
            #pragma unroll
            for (int off = 32; off > 0; off >>= 1) v += __shfl_down(v, off, 64);
            if (lane == 0) wsum[wid][p] = v;
        }
        __syncthreads();
        if (t < 16) {
            float s = wsum[0][t] + wsum[1][t] + wsum[2][t] + wsum[3][t];
            int m = m0 + (t >> 2), n = n0 + (t & 3);
            atomicAdd(&ws[m * 64 + n], s);
        }
    }
}

// Margin pass + finalize: one block of 256 threads over the 64x64 d matrix.
__global__ __launch_bounds__(256) void fused_pass2(const float* __restrict__ ws,
                                                   float* __restrict__ out) {
    const int t = threadIdx.x;
    const int lane = t & 63, wid = t >> 6;
    float p = 0.f, q = 0.f;
    #pragma unroll
    for (int s = 0; s < 16; s++) {
        int idx = t + s * 256;
        float d = ws[idx] * (1.0f / (float)DIMZ);
        int m = idx >> 6, n = idx & 63;
        if (m == n) { if (d > MARGIN_POS) p += d - MARGIN_POS; }
        else        { if (d < MARGIN_NEG) q += MARGIN_NEG - d; }
    }
    #pragma unroll
    for (int off = 32; off > 0; off >>= 1) {
        p += __shfl_down(p, off, 64);
        q += __shfl_down(q, off, 64);
    }
    __shared__ float sp[4], sq[4];
    if (lane == 0) { sp[wid] = p; sq[wid] = q; }
    __syncthreads();
    if (t == 0) {
        float P = sp[0] + sp[1] + sp[2] + sp[3];
        float Q = sq[0] + sq[1] + sq[2] + sq[3];
        float recon = ws[WS_MSE_IDX] * (1.0f / (float)N_ELEM);
        out[0] = recon + 1.5f * (P / (float)BATCH)
                       + 0.5f * (Q / (float)(BATCH * (BATCH - 1)));
    }
}

extern "C" void kernel_launch(void* const* d_in, const int* in_sizes, int n_in,
                              void* d_out, int out_size, void* d_ws, size_t ws_size,
                              hipStream_t stream) {
    const float* outputs1 = (const float*)d_in[0];
    const float* z1       = (const float*)d_in[1];
    const float* outputs2 = (const float*)d_in[2];
    const float* z2       = (const float*)d_in[3];
    const float* input1   = (const float*)d_in[4];
    const float* input2   = (const float*)d_in[5];
    float* out = (float*)d_out;
    float* ws  = (float*)d_ws;

    hipMemsetAsync(ws, 0, WS_FLOATS * sizeof(float), stream);

    fused_pass1<<<CB2 + MSEB, 256, 0, stream>>>(outputs1, input1, outputs2, input2,
                                                z1, z2, ws);
    fused_pass2<<<1, 256, 0, stream>>>(ws, out);
}

// Round 4
// 219.721 us; speedup vs baseline: 1.0928x; 1.0928x over previous
//
#include <hip/hip_runtime.h>

#define MARGIN_NEG 0.4f
#define MARGIN_POS 0.01f

// Problem constants: B=64, C=3, H=W=256 -> N = 12,582,912 elems; z: 64 x 16384
#define N_ELEM   12582912
#define N4       (N_ELEM / 4)          // 3,145,728 float4 per tensor
#define BATCH    64
#define DIMZ     16384
#define ROW4     (DIMZ / 4)            // 4096 float4 per z-row

// MSE: 2048 blocks per pair; each block streams a CONTIGUOUS 24-KB window
// (1536 float4) of A and of B: 6 unrolled iterations x 256 threads.
#define MSE_BPP   2048
#define MSEB      (2 * MSE_BPP)        // 4096 MSE blocks (first in grid)
#define F4_PER_BLK 1536                // 6 * 256
#define CB3       1024                 // contrastive blocks (last in grid)

// ws layout (floats), all plain stores (each slot written exactly once -> no memset):
//   [kc*4096 + m*64 + n], kc in 0..3 : contrastive partial d sums
//   [16384 + mseBlock]               : per-block MSE partial sums
#define D_OFF    0
#define MSE_OFF  16384

__global__ __launch_bounds__(256) void fused_pass1(
        const float* __restrict__ o1, const float* __restrict__ i1,
        const float* __restrict__ o2, const float* __restrict__ i2,
        const float* __restrict__ z1, const float* __restrict__ z2,
        float* __restrict__ ws) {
    const int b = blockIdx.x;
    const int t = threadIdx.x;
    const int lane = t & 63, wid = t >> 6;

    if (b < MSEB) {
        // ---------------- MSE: contiguous streaming, no atomics ----------------
        const int pair = b >> 11;                 // 0..1
        const int mb   = b & (MSE_BPP - 1);       // 0..2047
        const float4* A  = pair ? (const float4*)o2 : (const float4*)o1;
        const float4* Bv = pair ? (const float4*)i2 : (const float4*)i1;
        const int base = mb * F4_PER_BLK + t;

        // Issue all 12 loads before any compute (independent dests).
        float4 a[6], bb[6];
        #pragma unroll
        for (int s = 0; s < 6; s++) a[s]  = A[base + s * 256];
        #pragma unroll
        for (int s = 0; s < 6; s++) bb[s] = Bv[base + s * 256];

        float acc0 = 0.f, acc1 = 0.f;
        #pragma unroll
        for (int s = 0; s < 6; s += 2) {
            float x0 = a[s].x - bb[s].x, x1 = a[s].y - bb[s].y;
            float x2 = a[s].z - bb[s].z, x3 = a[s].w - bb[s].w;
            acc0 += x0 * x0 + x1 * x1 + x2 * x2 + x3 * x3;
            float y0 = a[s+1].x - bb[s+1].x, y1 = a[s+1].y - bb[s+1].y;
            float y2 = a[s+1].z - bb[s+1].z, y3 = a[s+1].w - bb[s+1].w;
            acc1 += y0 * y0 + y1 * y1 + y2 * y2 + y3 * y3;
        }
        float v = acc0 + acc1;
        #pragma unroll
        for (int off = 32; off > 0; off >>= 1) v += __shfl_down(v, off, 64);
        __shared__ float ws4[4];
        if (lane == 0) ws4[wid] = v;
        __syncthreads();
        if (t == 0) ws[MSE_OFF + b] = ws4[0] + ws4[1] + ws4[2] + ws4[3];  // plain store
    } else {
        // ---- contrastive: partial sums of sum_k (z1[m,k]-z2[n,k])^2, k-split x4 ----
        const int cb   = b - MSEB;
        const int kc   = cb & 3;            // k-chunk: 1024 float4 = 4096 floats
        const int tile = cb >> 2;           // 0..255
        const int m0 = (tile >> 4) * 4;
        const int n0 = (tile & 15) * 4;
        const float4* z1v = (const float4*)z1;
        const float4* z2v = (const float4*)z2;

        float acc[16];
        #pragma unroll
        for (int p = 0; p < 16; p++) acc[p] = 0.f;

        const int cbase = kc * 1024 + t;
        #pragma unroll
        for (int it = 0; it < 4; it++) {
            const int c = cbase + it * 256;
            float4 a[4], bz[4];
            #pragma unroll
            for (int i = 0; i < 4; i++) a[i] = z1v[(m0 + i) * ROW4 + c];
            #pragma unroll
            for (int j = 0; j < 4; j++) bz[j] = z2v[(n0 + j) * ROW4 + c];
            #pragma unroll
            for (int i = 0; i < 4; i++) {
                #pragma unroll
                for (int j = 0; j < 4; j++) {
                    float dx = a[i].x - bz[j].x, dy = a[i].y - bz[j].y;
                    float dz = a[i].z - bz[j].z, dw = a[i].w - bz[j].w;
                    acc[i * 4 + j] += dx * dx + dy * dy + dz * dz + dw * dw;
                }
            }
        }

        __shared__ float wsum[4][16];
        #pragma unroll
        for (int p = 0; p < 16; p++) {
            float v = acc[p];
            #pragma unroll
            for (int off = 32; off > 0; off >>= 1) v += __shfl_down(v, off, 64);
            if (lane == 0) wsum[wid][p] = v;
        }
        __syncthreads();
        if (t < 16) {
            float s = wsum[0][t] + wsum[1][t] + wsum[2][t] + wsum[3][t];
            int m = m0 + (t >> 2), n = n0 + (t & 3);
            ws[D_OFF + kc * 4096 + m * 64 + n] = s;   // plain store, unique slot
        }
    }
}

// Reduce partials + margins + finalize: one block of 256 threads.
__global__ __launch_bounds__(256) void fused_pass2(const float* __restrict__ ws,
                                                   float* __restrict__ out) {
    const int t = threadIdx.x;
    const int lane = t & 63, wid = t >> 6;

    float msum = 0.f;
    #pragma unroll
    for (int s = 0; s < 16; s++) msum += ws[MSE_OFF + t + s * 256];  // 4096 partials

    float p = 0.f, q = 0.f;
    #pragma unroll
    for (int s = 0; s < 16; s++) {
        int idx = t + s * 256;                                       // 4096 pairs
        float d = (ws[idx] + ws[4096 + idx] + ws[8192 + idx] + ws[12288 + idx])
                  * (1.0f / (float)DIMZ);
        int m = idx >> 6, n = idx & 63;
        if (m == n) { if (d > MARGIN_POS) p += d - MARGIN_POS; }
        else        { if (d < MARGIN_NEG) q += MARGIN_NEG - d; }
    }

    #pragma unroll
    for (int off = 32; off > 0; off >>= 1) {
        msum += __shfl_down(msum, off, 64);
        p    += __shfl_down(p,    off, 64);
        q    += __shfl_down(q,    off, 64);
    }
    __shared__ float sm[4], sp[4], sq[4];
    if (lane == 0) { sm[wid] = msum; sp[wid] = p; sq[wid] = q; }
    __syncthreads();
    if (t == 0) {
        float M = sm[0] + sm[1] + sm[2] + sm[3];
        float P = sp[0] + sp[1] + sp[2] + sp[3];
        float Q = sq[0] + sq[1] + sq[2] + sq[3];
        out[0] = M * (1.0f / (float)N_ELEM)
               + 1.5f * (P / (float)BATCH)
               + 0.5f * (Q / (float)(BATCH * (BATCH - 1)));
    }
}

extern "C" void kernel_launch(void* const* d_in, const int* in_sizes, int n_in,
                              void* d_out, int out_size, void* d_ws, size_t ws_size,
                              hipStream_t stream) {
    const float* outputs1 = (const float*)d_in[0];
    const float* z1       = (const float*)d_in[1];
    const float* outputs2 = (const float*)d_in[2];
    const float* z2       = (const float*)d_in[3];
    const float* input1   = (const float*)d_in[4];
    const float* input2   = (const float*)d_in[5];
    float* out = (float*)d_out;
    float* ws  = (float*)d_ws;

    fused_pass1<<<MSEB + CB3, 256, 0, stream>>>(outputs1, input1, outputs2, input2,
                                                z1, z2, ws);
    fused_pass2<<<1, 256, 0, stream>>>(ws, out);
}

// Round 6
// 202.026 us; speedup vs baseline: 1.1885x; 1.0876x over previous
//
#include <hip/hip_runtime.h>

#define MARGIN_NEG 0.4f
#define MARGIN_POS 0.01f

// Problem constants: B=64, C=3, H=W=256 -> N = 12,582,912 elems; z: 64 x 16384
#define N_ELEM   12582912
#define N4       (N_ELEM / 4)          // 3,145,728 float4 per tensor
#define BATCH    64
#define DIMZ     16384
#define ROW4     (DIMZ / 4)            // 4096 float4 per z-row

// Native clang vector type: required by __builtin_nontemporal_load.
typedef float vf4 __attribute__((ext_vector_type(4)));

// MSE: 1024 persistent blocks; each block owns a contiguous 48-KB window of
// each of the 4 streams (3072 float4 = 12 per thread per stream), processed as
// 3 iterations x (4 float4 from each of 4 streams) = 16 nontemporal loads in
// flight per thread per iteration.
#define MSE_BLKS  1024
#define F4_PER_STREAM_BLK 3072         // N4 / MSE_BLKS
#define CB        1024                 // contrastive blocks (second half of grid)

// ws layout (floats), all plain stores, every slot written exactly once:
//   [kc*4096 + m*64 + n], kc in 0..3 : contrastive partial d sums   (16384)
//   [16384 + mseBlock]               : per-block MSE partials       (1024)
#define MSE_OFF  16384

__global__ __launch_bounds__(256) void fused_pass1(
        const float* __restrict__ o1, const float* __restrict__ i1,
        const float* __restrict__ o2, const float* __restrict__ i2,
        const float* __restrict__ z1, const float* __restrict__ z2,
        float* __restrict__ ws) {
    const int b = blockIdx.x;
    const int t = threadIdx.x;
    const int lane = t & 63, wid = t >> 6;

    if (b < MSE_BLKS) {
        // ------- MSE: persistent, nontemporal streaming, deep ILP -------
        const vf4* A1 = (const vf4*)o1;
        const vf4* B1 = (const vf4*)i1;
        const vf4* A2 = (const vf4*)o2;
        const vf4* B2 = (const vf4*)i2;
        const int base = b * F4_PER_STREAM_BLK + t;   // stream-local f4 index

        float acc0 = 0.f, acc1 = 0.f, acc2 = 0.f, acc3 = 0.f;
        #pragma unroll
        for (int it = 0; it < 3; it++) {
            vf4 a1[4], b1[4], a2[4], b2[4];
            #pragma unroll
            for (int j = 0; j < 4; j++) {
                const int idx = base + (it * 4 + j) * 256;
                a1[j] = __builtin_nontemporal_load(&A1[idx]);
                b1[j] = __builtin_nontemporal_load(&B1[idx]);
                a2[j] = __builtin_nontemporal_load(&A2[idx]);
                b2[j] = __builtin_nontemporal_load(&B2[idx]);
            }
            #pragma unroll
            for (int j = 0; j < 4; j++) {
                vf4 d1 = a1[j] - b1[j];
                vf4 d2 = a2[j] - b2[j];
                acc0 += d1.x * d1.x + d1.y * d1.y;
                acc1 += d1.z * d1.z + d1.w * d1.w;
                acc2 += d2.x * d2.x + d2.y * d2.y;
                acc3 += d2.z * d2.z + d2.w * d2.w;
            }
        }
        float v = (acc0 + acc1) + (acc2 + acc3);
        #pragma unroll
        for (int off = 32; off > 0; off >>= 1) v += __shfl_down(v, off, 64);
        __shared__ float ws4[4];
        if (lane == 0) ws4[wid] = v;
        __syncthreads();
        if (t == 0) ws[MSE_OFF + b] = ws4[0] + ws4[1] + ws4[2] + ws4[3];
    } else {
        // ---- contrastive: partial sums of sum_k (z1[m,k]-z2[n,k])^2, k-split x4 ----
        const int cb   = b - MSE_BLKS;
        const int kc   = cb & 3;            // k-chunk: 1024 float4 = 4096 floats
        const int tile = cb >> 2;           // 0..255
        const int m0 = (tile >> 4) * 4;
        const int n0 = (tile & 15) * 4;
        const float4* z1v = (const float4*)z1;
        const float4* z2v = (const float4*)z2;

        float acc[16];
        #pragma unroll
        for (int p = 0; p < 16; p++) acc[p] = 0.f;

        const int cbase = kc * 1024 + t;
        #pragma unroll
        for (int it = 0; it < 4; it++) {
            const int c = cbase + it * 256;
            float4 a[4], bz[4];
            #pragma unroll
            for (int i = 0; i < 4; i++) a[i] = z1v[(m0 + i) * ROW4 + c];
            #pragma unroll
            for (int j = 0; j < 4; j++) bz[j] = z2v[(n0 + j) * ROW4 + c];
            #pragma unroll
            for (int i = 0; i < 4; i++) {
                #pragma unroll
                for (int j = 0; j < 4; j++) {
                    float dx = a[i].x - bz[j].x, dy = a[i].y - bz[j].y;
                    float dz = a[i].z - bz[j].z, dw = a[i].w - bz[j].w;
                    acc[i * 4 + j] += dx * dx + dy * dy + dz * dz + dw * dw;
                }
            }
        }

        __shared__ float wsum[4][16];
        #pragma unroll
        for (int p = 0; p < 16; p++) {
            float v = acc[p];
            #pragma unroll
            for (int off = 32; off > 0; off >>= 1) v += __shfl_down(v, off, 64);
            if (lane == 0) wsum[wid][p] = v;
        }
        __syncthreads();
        if (t < 16) {
            float s = wsum[0][t] + wsum[1][t] + wsum[2][t] + wsum[3][t];
            int m = m0 + (t >> 2), n = n0 + (t & 3);
            ws[kc * 4096 + m * 64 + n] = s;   // plain store, unique slot
        }
    }
}

// Reduce partials + margins + finalize: one block of 256 threads.
__global__ __launch_bounds__(256) void fused_pass2(const float* __restrict__ ws,
                                                   float* __restrict__ out) {
    const int t = threadIdx.x;
    const int lane = t & 63, wid = t >> 6;

    float msum = 0.f;
    #pragma unroll
    for (int s = 0; s < 4; s++) msum += ws[MSE_OFF + t + s * 256];   // 1024 partials

    float p = 0.f, q = 0.f;
    #pragma unroll
    for (int s = 0; s < 16; s++) {
        int idx = t + s * 256;                                       // 4096 pairs
        float d = (ws[idx] + ws[4096 + idx] + ws[8192 + idx] + ws[12288 + idx])
                  * (1.0f / (float)DIMZ);
        int m = idx >> 6, n = idx & 63;
        if (m == n) { if (d > MARGIN_POS) p += d - MARGIN_POS; }
        else        { if (d < MARGIN_NEG) q += MARGIN_NEG - d; }
    }

    #pragma unroll
    for (int off = 32; off > 0; off >>= 1) {
        msum += __shfl_down(msum, off, 64);
        p    += __shfl_down(p,    off, 64);
        q    += __shfl_down(q,    off, 64);
    }
    __shared__ float sm[4], sp[4], sq[4];
    if (lane == 0) { sm[wid] = msum; sp[wid] = p; sq[wid] = q; }
    __syncthreads();
    if (t == 0) {
        float M = sm[0] + sm[1] + sm[2] + sm[3];
        float P = sp[0] + sp[1] + sp[2] + sp[3];
        float Q = sq[0] + sq[1] + sq[2] + sq[3];
        out[0] = M * (1.0f / (float)N_ELEM)
               + 1.5f * (P / (float)BATCH)
               + 0.5f * (Q / (float)(BATCH * (BATCH - 1)));
    }
}

extern "C" void kernel_launch(void* const* d_in, const int* in_sizes, int n_in,
                              void* d_out, int out_size, void* d_ws, size_t ws_size,
                              hipStream_t stream) {
    const float* outputs1 = (const float*)d_in[0];
    const float* z1       = (const float*)d_in[1];
    const float* outputs2 = (const float*)d_in[2];
    const float* z2       = (const float*)d_in[3];
    const float* input1   = (const float*)d_in[4];
    const float* input2   = (const float*)d_in[5];
    float* out = (float*)d_out;
    float* ws  = (float*)d_ws;

    fused_pass1<<<MSE_BLKS + CB, 256, 0, stream>>>(outputs1, input1, outputs2, input2,
                                                   z1, z2, ws);
    fused_pass2<<<1, 256, 0, stream>>>(ws, out);
}

// Round 7
// 201.547 us; speedup vs baseline: 1.1913x; 1.0024x over previous
//
#include <hip/hip_runtime.h>

#define MARGIN_NEG 0.4f
#define MARGIN_POS 0.01f

// Problem constants: B=64, C=3, H=W=256 -> N = 12,582,912 elems; z: 64 x 16384
#define N_ELEM   12582912
#define N4       (N_ELEM / 4)          // 3,145,728 float4 per tensor
#define BATCH    64
#define DIMZ     16384
#define ROW4     (DIMZ / 4)            // 4096 float4 per z-row

// Native clang vector type: required by __builtin_nontemporal_load.
typedef float vf4 __attribute__((ext_vector_type(4)));

// MSE: 3072 blocks; each block owns a contiguous 16-KB window (1024 float4)
// of each of the 4 streams. Each thread issues ALL 16 of its nt loads in one
// batch (256 B in flight), computes, reduces, exits. Block churn sustains
// memory-level parallelism; no inter-batch drain points.
#define MSE_BLKS  3072
#define F4_PER_STREAM_BLK 1024         // N4 / MSE_BLKS
#define CB        1024                 // contrastive blocks (last in grid)

// ws layout (floats), all plain stores, every slot written exactly once:
//   [kc*4096 + m*64 + n], kc in 0..3 : contrastive partial d sums   (16384)
//   [16384 + mseBlock]               : per-block MSE partials       (3072)
#define MSE_OFF  16384

__global__ __launch_bounds__(256) void fused_pass1(
        const float* __restrict__ o1, const float* __restrict__ i1,
        const float* __restrict__ o2, const float* __restrict__ i2,
        const float* __restrict__ z1, const float* __restrict__ z2,
        float* __restrict__ ws) {
    const int b = blockIdx.x;
    const int t = threadIdx.x;
    const int lane = t & 63, wid = t >> 6;

    if (b < MSE_BLKS) {
        // ------- MSE: single-batch nt streaming, max block churn -------
        const vf4* A1 = (const vf4*)o1;
        const vf4* B1 = (const vf4*)i1;
        const vf4* A2 = (const vf4*)o2;
        const vf4* B2 = (const vf4*)i2;
        const int base = b * F4_PER_STREAM_BLK + t;   // stream-local f4 index

        vf4 a1[4], a2[4], b1[4], b2[4];
        // Grouped by stream: same-offset A/B pairs separated in issue order.
        #pragma unroll
        for (int j = 0; j < 4; j++) a1[j] = __builtin_nontemporal_load(&A1[base + j * 256]);
        #pragma unroll
        for (int j = 0; j < 4; j++) a2[j] = __builtin_nontemporal_load(&A2[base + j * 256]);
        #pragma unroll
        for (int j = 0; j < 4; j++) b1[j] = __builtin_nontemporal_load(&B1[base + j * 256]);
        #pragma unroll
        for (int j = 0; j < 4; j++) b2[j] = __builtin_nontemporal_load(&B2[base + j * 256]);

        float acc0 = 0.f, acc1 = 0.f, acc2 = 0.f, acc3 = 0.f;
        #pragma unroll
        for (int j = 0; j < 4; j++) {
            vf4 d1 = a1[j] - b1[j];
            vf4 d2 = a2[j] - b2[j];
            acc0 += d1.x * d1.x + d1.y * d1.y;
            acc1 += d1.z * d1.z + d1.w * d1.w;
            acc2 += d2.x * d2.x + d2.y * d2.y;
            acc3 += d2.z * d2.z + d2.w * d2.w;
        }
        float v = (acc0 + acc1) + (acc2 + acc3);
        #pragma unroll
        for (int off = 32; off > 0; off >>= 1) v += __shfl_down(v, off, 64);
        __shared__ float ws4[4];
        if (lane == 0) ws4[wid] = v;
        __syncthreads();
        if (t == 0) ws[MSE_OFF + b] = ws4[0] + ws4[1] + ws4[2] + ws4[3];
    } else {
        // ---- contrastive: partial sums of sum_k (z1[m,k]-z2[n,k])^2, k-split x4 ----
        const int cb   = b - MSE_BLKS;
        const int kc   = cb & 3;            // k-chunk: 1024 float4 = 4096 floats
        const int tile = cb >> 2;           // 0..255
        const int m0 = (tile >> 4) * 4;
        const int n0 = (tile & 15) * 4;
        const float4* z1v = (const float4*)z1;
        const float4* z2v = (const float4*)z2;

        float acc[16];
        #pragma unroll
        for (int p = 0; p < 16; p++) acc[p] = 0.f;

        const int cbase = kc * 1024 + t;
        #pragma unroll
        for (int it = 0; it < 4; it++) {
            const int c = cbase + it * 256;
            float4 a[4], bz[4];
            #pragma unroll
            for (int i = 0; i < 4; i++) a[i] = z1v[(m0 + i) * ROW4 + c];
            #pragma unroll
            for (int j = 0; j < 4; j++) bz[j] = z2v[(n0 + j) * ROW4 + c];
            #pragma unroll
            for (int i = 0; i < 4; i++) {
                #pragma unroll
                for (int j = 0; j < 4; j++) {
                    float dx = a[i].x - bz[j].x, dy = a[i].y - bz[j].y;
                    float dz = a[i].z - bz[j].z, dw = a[i].w - bz[j].w;
                    acc[i * 4 + j] += dx * dx + dy * dy + dz * dz + dw * dw;
                }
            }
        }

        __shared__ float wsum[4][16];
        #pragma unroll
        for (int p = 0; p < 16; p++) {
            float v = acc[p];
            #pragma unroll
            for (int off = 32; off > 0; off >>= 1) v += __shfl_down(v, off, 64);
            if (lane == 0) wsum[wid][p] = v;
        }
        __syncthreads();
        if (t < 16) {
            float s = wsum[0][t] + wsum[1][t] + wsum[2][t] + wsum[3][t];
            int m = m0 + (t >> 2), n = n0 + (t & 3);
            ws[kc * 4096 + m * 64 + n] = s;   // plain store, unique slot
        }
    }
}

// Reduce partials + margins + finalize: one block of 256 threads.
__global__ __launch_bounds__(256) void fused_pass2(const float* __restrict__ ws,
                                                   float* __restrict__ out) {
    const int t = threadIdx.x;
    const int lane = t & 63, wid = t >> 6;

    float msum = 0.f;
    #pragma unroll
    for (int s = 0; s < 12; s++) msum += ws[MSE_OFF + t + s * 256];  // 3072 partials

    float p = 0.f, q = 0.f;
    #pragma unroll
    for (int s = 0; s < 16; s++) {
        int idx = t + s * 256;                                       // 4096 pairs
        float d = (ws[idx] + ws[4096 + idx] + ws[8192 + idx] + ws[12288 + idx])
                  * (1.0f / (float)DIMZ);
        int m = idx >> 6, n = idx & 63;
        if (m == n) { if (d > MARGIN_POS) p += d - MARGIN_POS; }
        else        { if (d < MARGIN_NEG) q += MARGIN_NEG - d; }
    }

    #pragma unroll
    for (int off = 32; off > 0; off >>= 1) {
        msum += __shfl_down(msum, off, 64);
        p    += __shfl_down(p,    off, 64);
        q    += __shfl_down(q,    off, 64);
    }
    __shared__ float sm[4], sp[4], sq[4];
    if (lane == 0) { sm[wid] = msum; sp[wid] = p; sq[wid] = q; }
    __syncthreads();
    if (t == 0) {
        float M = sm[0] + sm[1] + sm[2] + sm[3];
        float P = sp[0] + sp[1] + sp[2] + sp[3];
        float Q = sq[0] + sq[1] + sq[2] + sq[3];
        out[0] = M * (1.0f / (float)N_ELEM)
               + 1.5f * (P / (float)BATCH)
               + 0.5f * (Q / (float)(BATCH * (BATCH - 1)));
    }
}

extern "C" void kernel_launch(void* const* d_in, const int* in_sizes, int n_in,
                              void* d_out, int out_size, void* d_ws, size_t ws_size,
                              hipStream_t stream) {
    const float* outputs1 = (const float*)d_in[0];
    const float* z1       = (const float*)d_in[1];
    const float* outputs2 = (const float*)d_in[2];
    const float* z2       = (const float*)d_in[3];
    const float* input1   = (const float*)d_in[4];
    const float* input2   = (const float*)d_in[5];
    float* out = (float*)d_out;
    float* ws  = (float*)d_ws;

    fused_pass1<<<MSE_BLKS + CB, 256, 0, stream>>>(outputs1, input1, outputs2, input2,
                                                   z1, z2, ws);
    fused_pass2<<<1, 256, 0, stream>>>(ws, out);
}